// Round 1
// baseline (682.208 us; speedup 1.0000x reference)
//
#include <hip/hip_runtime.h>
#include <hip/hip_fp16.h>
#include <math.h>

// Problem dims
#define B_ 8
#define H_ 640
#define W_ 368
#define HW_ (H_*W_)
#define NP_ (B_*H_*W_)   // 1,884,160

#define LINES 8   // lines per block in W-axis DFT
#define KT 8      // k-tile in H-axis DFT

__device__ __forceinline__ float leaky_(float x){ return x >= 0.f ? x : 0.01f*x; }

// ---------------------------------------------------------------------------
// K0: build centered-ifft matrix  M[k][n] = (1/sqrt(N)) * (-1)^(k+n) * e^{+2pi i kn/N}
// (shift-fold valid: N even and N % 4 == 0 for all three axes)
// ---------------------------------------------------------------------------
__global__ void dft_mat_kernel(float2* __restrict__ M, int N, float scale){
    int idx = blockIdx.x*blockDim.x + threadIdx.x;
    if (idx >= N*N) return;
    int k = idx / N, n = idx % N;
    int t = (int)(((long long)k * n) % N);
    if (t > N/2) t -= N;                       // center for sincos accuracy
    float ang = (float)(6.283185307179586 * ((double)t / (double)N));
    float s, c;
    sincosf(ang, &s, &c);
    float sgn = ((k + n) & 1) ? -scale : scale;
    M[idx] = make_float2(c*sgn, s*sgn);
}

// ---------------------------------------------------------------------------
// K1: fused k-branch: conv3x3(2->32,pad1)+leaky -> conv1x1(32->2)+leaky
//     writes complex plane A[b][h][w] = (ch0, ch1)
// ---------------------------------------------------------------------------
__global__ void kbranch_kernel(const float* __restrict__ ksp,
                               const float* __restrict__ wk,
                               const float* __restrict__ bk,
                               const float* __restrict__ w1,
                               const float* __restrict__ b1,
                               float2* __restrict__ A){
    int idx = blockIdx.x*blockDim.x + threadIdx.x;
    if (idx >= NP_) return;
    int w = idx % W_;
    int h = (idx / W_) % H_;
    int b = idx / HW_;

    float v[2][3][3];
    #pragma unroll
    for (int ic = 0; ic < 2; ++ic)
        #pragma unroll
        for (int dy = 0; dy < 3; ++dy){
            int hh = h + dy - 1;
            #pragma unroll
            for (int dx = 0; dx < 3; ++dx){
                int ww = w + dx - 1;
                v[ic][dy][dx] = (hh >= 0 && hh < H_ && ww >= 0 && ww < W_)
                              ? ksp[((b*2+ic)*H_ + hh)*W_ + ww] : 0.f;
            }
        }

    float t0 = b1[0], t1 = b1[1];
    for (int oc = 0; oc < 32; ++oc){
        float acc = bk[oc];
        #pragma unroll
        for (int ic = 0; ic < 2; ++ic)
            #pragma unroll
            for (int dy = 0; dy < 3; ++dy)
                #pragma unroll
                for (int dx = 0; dx < 3; ++dx)
                    acc += wk[((oc*2+ic)*3+dy)*3+dx] * v[ic][dy][dx];
        acc = leaky_(acc);
        t0 += w1[oc]      * acc;
        t1 += w1[32 + oc] * acc;
    }
    A[idx] = make_float2(leaky_(t0), leaky_(t1));
}

// ---------------------------------------------------------------------------
// K2: W-axis DFT.  One block = LINES consecutive (b,h) lines.
//     LDS layout lds[n][line] so per-n reads are 4x ds_read_b128 broadcasts.
//     Matrix read MW[n*W+k]: coalesced across threads (M symmetric).
// ---------------------------------------------------------------------------
__global__ __launch_bounds__(384) void dftW_kernel(const float2* __restrict__ A,
                                                   const float2* __restrict__ MW,
                                                   float2* __restrict__ Bo){
    __shared__ float2 lds[W_][LINES];
    int tid = threadIdx.x;
    int base = blockIdx.x * (LINES * W_);

    for (int i = tid; i < LINES*W_; i += 384){
        int l = i / W_, n = i % W_;
        lds[n][l] = A[base + l*W_ + n];
    }
    __syncthreads();

    int k = tid;
    if (k < W_){
        float ar[LINES], ai[LINES];
        #pragma unroll
        for (int l = 0; l < LINES; ++l){ ar[l] = 0.f; ai[l] = 0.f; }

        for (int n = 0; n < W_; ++n){
            float2 m = MW[n*W_ + k];
            const float4* row = (const float4*)&lds[n][0];
            #pragma unroll
            for (int q = 0; q < LINES/2; ++q){
                float4 p = row[q];
                ar[2*q]   += m.x*p.x - m.y*p.y;
                ai[2*q]   += m.x*p.y + m.y*p.x;
                ar[2*q+1] += m.x*p.z - m.y*p.w;
                ai[2*q+1] += m.x*p.w + m.y*p.z;
            }
        }
        #pragma unroll
        for (int l = 0; l < LINES; ++l)
            Bo[base + l*W_ + k] = make_float2(ar[l], ai[l]);
    }
}

// ---------------------------------------------------------------------------
// K3: H-axis DFT. Block = (b, tile of KT output rows), threads over w.
//     x loads coalesced; matrix loads wave-uniform (scalar path), contiguous
//     8 x float2 at MH[n*H + k0..k0+7] (M symmetric).
// ---------------------------------------------------------------------------
__global__ __launch_bounds__(384) void dftH_kernel(const float2* __restrict__ Bi,
                                                   const float2* __restrict__ MH,
                                                   float2* __restrict__ Ao){
    int w = threadIdx.x;
    int bidx = blockIdx.x;                 // b*(H/KT) + ktile
    int b  = bidx / (H_/KT);
    int k0 = (bidx % (H_/KT)) * KT;
    if (w >= W_) return;

    const float2* xp = Bi + b*HW_ + w;
    float ar[KT], ai[KT];
    #pragma unroll
    for (int j = 0; j < KT; ++j){ ar[j] = 0.f; ai[j] = 0.f; }

    #pragma unroll 4
    for (int n = 0; n < H_; ++n){
        float2 x = xp[n*W_];
        #pragma unroll
        for (int j = 0; j < KT; ++j){
            float2 m = MH[n*H_ + k0 + j];
            ar[j] += m.x*x.x - m.y*x.y;
            ai[j] += m.x*x.y + m.y*x.x;
        }
    }
    #pragma unroll
    for (int j = 0; j < KT; ++j)
        Ao[(b*H_ + k0 + j)*W_ + w] = make_float2(ar[j], ai[j]);
}

// ---------------------------------------------------------------------------
// K4: B-axis DFT (N=8) + magnitude + fp16-emulated conv2(1x1, [im,img]->1) + leaky
// ---------------------------------------------------------------------------
__global__ void bdft_mag_conv2_kernel(const float2* __restrict__ A,
                                      const float2* __restrict__ MB,
                                      const float* __restrict__ img,
                                      const float* __restrict__ w2,
                                      const float* __restrict__ b2,
                                      float* __restrict__ P){
    __shared__ float2 mb[64];
    int tid = threadIdx.x;
    if (tid < 64) mb[tid] = MB[tid];
    __syncthreads();

    int hw = blockIdx.x*blockDim.x + tid;
    if (hw >= HW_) return;

    float xr[8], xi[8];
    #pragma unroll
    for (int n = 0; n < 8; ++n){
        float2 x = A[n*HW_ + hw];
        xr[n] = x.x; xi[n] = x.y;
    }
    float w2h0 = __half2float(__float2half(w2[0]));
    float w2h1 = __half2float(__float2half(w2[1]));
    float b2h  = __half2float(__float2half(b2[0]));

    #pragma unroll
    for (int k = 0; k < 8; ++k){
        float yr = 0.f, yi = 0.f;
        #pragma unroll
        for (int n = 0; n < 8; ++n){
            float2 m = mb[k*8 + n];
            yr += m.x*xr[n] - m.y*xi[n];
            yi += m.x*xi[n] + m.y*xr[n];
        }
        float mag = sqrtf(yr*yr + yi*yi);
        float a = __half2float(__float2half(mag));
        float g = __half2float(__float2half(img[k*HW_ + hw]));
        float o = a*w2h0 + g*w2h1 + b2h;
        o = leaky_(o);
        o = __half2float(__float2half(o));
        P[k*HW_ + hw] = o;
    }
}

// ---------------------------------------------------------------------------
// K5: image-domain conv3x3(1->1, pad1) + leaky -> d_out
// ---------------------------------------------------------------------------
__global__ void conv_i_kernel(const float* __restrict__ P,
                              const float* __restrict__ wi,
                              const float* __restrict__ bi,
                              float* __restrict__ out){
    int idx = blockIdx.x*blockDim.x + threadIdx.x;
    if (idx >= NP_) return;
    int w = idx % W_;
    int h = (idx / W_) % H_;
    int b = idx / HW_;

    float acc = bi[0];
    #pragma unroll
    for (int dy = 0; dy < 3; ++dy){
        int hh = h + dy - 1;
        if (hh < 0 || hh >= H_) continue;
        #pragma unroll
        for (int dx = 0; dx < 3; ++dx){
            int ww = w + dx - 1;
            if (ww < 0 || ww >= W_) continue;
            acc += wi[dy*3+dx] * P[(b*H_ + hh)*W_ + ww];
        }
    }
    out[idx] = leaky_(acc);
}

// ---------------------------------------------------------------------------
// Workspace layout (bytes):
//   A  : float2[NP]            @ 0           (15,073,280)
//   B  : float2[NP]            @ 15,073,280  (15,073,280)   (P aliases B)
//   MW : float2[368*368]       @ 30,146,560  ( 1,083,392)
//   MH : float2[640*640]       @ 31,229,952  ( 3,276,800)
//   MB : float2[64]            @ 34,506,752  (       512)
// total ~34.5 MB
// ---------------------------------------------------------------------------
extern "C" void kernel_launch(void* const* d_in, const int* in_sizes, int n_in,
                              void* d_out, int out_size, void* d_ws, size_t ws_size,
                              hipStream_t stream){
    const float* img = (const float*)d_in[0];
    const float* ksp = (const float*)d_in[1];
    const float* wk  = (const float*)d_in[2];
    const float* bk  = (const float*)d_in[3];
    const float* w1  = (const float*)d_in[4];
    const float* b1  = (const float*)d_in[5];
    const float* w2  = (const float*)d_in[6];
    const float* b2  = (const float*)d_in[7];
    const float* wi  = (const float*)d_in[8];
    const float* bi  = (const float*)d_in[9];

    char* ws = (char*)d_ws;
    float2* A  = (float2*)(ws + 0);
    float2* Bb = (float2*)(ws + 15073280);
    float2* MW = (float2*)(ws + 30146560);
    float2* MH = (float2*)(ws + 31229952);
    float2* MB = (float2*)(ws + 34506752);
    float*  P  = (float*)Bb;                 // reuse B region after H-pass
    float* out = (float*)d_out;

    // twiddle matrices (ws is re-poisoned every call -> rebuild every call)
    dft_mat_kernel<<<(W_*W_ + 255)/256, 256, 0, stream>>>(MW, W_, 1.f/sqrtf((float)W_));
    dft_mat_kernel<<<(H_*H_ + 255)/256, 256, 0, stream>>>(MH, H_, 1.f/sqrtf((float)H_));
    dft_mat_kernel<<<1, 64, 0, stream>>>(MB, 8, 1.f/sqrtf(8.f));

    kbranch_kernel<<<(NP_ + 255)/256, 256, 0, stream>>>(ksp, wk, bk, w1, b1, A);

    dftW_kernel<<<(B_*H_)/LINES, 384, 0, stream>>>(A, MW, Bb);      // A -> B
    dftH_kernel<<<B_*(H_/KT), 384, 0, stream>>>(Bb, MH, A);         // B -> A

    bdft_mag_conv2_kernel<<<(HW_ + 255)/256, 256, 0, stream>>>(A, MB, img, w2, b2, P);

    conv_i_kernel<<<(NP_ + 255)/256, 256, 0, stream>>>(P, wi, bi, out);
}

// Round 2
// 260.930 us; speedup vs baseline: 2.6145x; 2.6145x over previous
//
#include <hip/hip_runtime.h>
#include <hip/hip_fp16.h>
#include <math.h>

// Problem dims
#define B_ 8
#define H_ 640
#define W_ 368
#define HW_ (H_*W_)
#define NP_ (B_*H_*W_)   // 1,884,160

#define WLINES 16        // lines per block in W-axis FFT
#define HCOLS 8          // columns per block in H-axis FFT
#define HPITCH 9         // LDS row pitch (float2) for H kernel

__device__ __forceinline__ float leaky_(float x){ return x >= 0.f ? x : 0.01f*x; }

// ---------------------------------------------------------------------------
// Table region (float2 indices within T):
//   F16   @    0  (256)   e^{+2pi i kn/16}
//   F23   @  256  (529)   e^{+2pi i kn/23}
//   TW368 @  785  (368)   e^{+2pi i k1*n2/368}, k1 in [0,16), n2 in [0,23)
//   F40   @ 1153  (1600)  e^{+2pi i kn/40}
//   TW640 @ 2753  (640)   e^{+2pi i k1*n2/640}, k1 in [0,16), n2 in [0,40)
//   MB    @ 3393  (64)    centered+scaled 8x8 ifft matrix
// total 3457 float2
// ---------------------------------------------------------------------------
__global__ void init_tables_kernel(float2* __restrict__ T){
    int i = blockIdx.x*blockDim.x + threadIdx.x;
    if (i >= 3457) return;
    int r, c, modN; float scale = 1.f; int cent = 0; int j;
    if      (i <  256){ j = i;        r = j/16; c = j%16; modN = 16;  }
    else if (i <  785){ j = i-256;    r = j/23; c = j%23; modN = 23;  }
    else if (i < 1153){ j = i-785;    r = j/23; c = j%23; modN = 368; }
    else if (i < 2753){ j = i-1153;   r = j/40; c = j%40; modN = 40;  }
    else if (i < 3393){ j = i-2753;   r = j/40; c = j%40; modN = 640; }
    else              { j = i-3393;   r = j/8;  c = j%8;  modN = 8;
                        scale = 0.35355339059327373f; cent = 1; }
    int t = (int)(((long long)r * c) % modN);
    if (t > modN/2) t -= modN;
    float ang = (float)(6.283185307179586 * ((double)t / (double)modN));
    float s, co;
    sincosf(ang, &s, &co);
    if (cent && ((r + c) & 1)) scale = -scale;
    T[i] = make_float2(co*scale, s*scale);
}

// ---------------------------------------------------------------------------
// K1: fused k-branch: conv3x3(2->32,pad1)+leaky -> conv1x1(32->2)+leaky
// ---------------------------------------------------------------------------
__global__ void kbranch_kernel(const float* __restrict__ ksp,
                               const float* __restrict__ wk,
                               const float* __restrict__ bk,
                               const float* __restrict__ w1,
                               const float* __restrict__ b1,
                               float2* __restrict__ A){
    int idx = blockIdx.x*blockDim.x + threadIdx.x;
    if (idx >= NP_) return;
    int w = idx % W_;
    int h = (idx / W_) % H_;
    int b = idx / HW_;

    float v[2][3][3];
    #pragma unroll
    for (int ic = 0; ic < 2; ++ic)
        #pragma unroll
        for (int dy = 0; dy < 3; ++dy){
            int hh = h + dy - 1;
            #pragma unroll
            for (int dx = 0; dx < 3; ++dx){
                int ww = w + dx - 1;
                v[ic][dy][dx] = (hh >= 0 && hh < H_ && ww >= 0 && ww < W_)
                              ? ksp[((b*2+ic)*H_ + hh)*W_ + ww] : 0.f;
            }
        }

    float t0 = b1[0], t1 = b1[1];
    for (int oc = 0; oc < 32; ++oc){
        float acc = bk[oc];
        #pragma unroll
        for (int ic = 0; ic < 2; ++ic)
            #pragma unroll
            for (int dy = 0; dy < 3; ++dy)
                #pragma unroll
                for (int dx = 0; dx < 3; ++dx)
                    acc += wk[((oc*2+ic)*3+dy)*3+dx] * v[ic][dy][dx];
        acc = leaky_(acc);
        t0 += w1[oc]      * acc;
        t1 += w1[32 + oc] * acc;
    }
    A[idx] = make_float2(leaky_(t0), leaky_(t1));
}

// ---------------------------------------------------------------------------
// K2: W-axis centered IFFT, W = 368 = 16*23.
//   n = 23*n1 + n2, k = k1 + 16*k2
//   stage 1: DFT16 over n1 per (line,n2), twiddle e^{2pi i k1 n2/368}
//   stage 2: DFT23 over n2 per (line,k1)
//   centering: (-1)^n at load, (-1)^k * 1/sqrt(368) at store.
// ---------------------------------------------------------------------------
__global__ __launch_bounds__(256) void fftW_kernel(const float2* __restrict__ A,
                                                   const float2* __restrict__ F16,
                                                   const float2* __restrict__ F23,
                                                   const float2* __restrict__ TW,
                                                   float2* __restrict__ Bo){
    __shared__ float2 X[WLINES*368];
    int t = threadIdx.x;
    size_t base = (size_t)blockIdx.x * (WLINES*368);

    for (int i = t; i < WLINES*368; i += 256){
        float2 v = A[base + i];
        float s = (i & 1) ? -1.f : 1.f;          // (-1)^n (368 even)
        X[i] = make_float2(v.x*s, v.y*s);
    }
    __syncthreads();

    // stage 1: 16 lines * 23 n2 = 368 items
    for (int it = t; it < WLINES*23; it += 256){
        int l = it / 23, n2 = it % 23;
        float2 xin[16];
        #pragma unroll
        for (int n1 = 0; n1 < 16; ++n1) xin[n1] = X[l*368 + 23*n1 + n2];
        for (int k1 = 0; k1 < 16; ++k1){
            float ar = 0.f, ai = 0.f;
            #pragma unroll
            for (int n1 = 0; n1 < 16; ++n1){
                float2 f = F16[k1*16 + n1];       // uniform addr -> s_load
                ar += f.x*xin[n1].x - f.y*xin[n1].y;
                ai += f.x*xin[n1].y + f.y*xin[n1].x;
            }
            float2 w = TW[k1*23 + n2];
            X[l*368 + 23*k1 + n2] = make_float2(ar*w.x - ai*w.y, ar*w.y + ai*w.x);
        }
    }
    __syncthreads();

    // stage 2: 16 lines * 16 k1 = 256 items, one per thread
    {
        int l = t >> 4, k1 = t & 15;
        float2 a[23];
        #pragma unroll
        for (int n2 = 0; n2 < 23; ++n2) a[n2] = X[l*368 + 23*k1 + n2];
        __syncthreads();
        for (int k2 = 0; k2 < 23; ++k2){
            float ar = 0.f, ai = 0.f;
            #pragma unroll
            for (int n2 = 0; n2 < 23; ++n2){
                float2 f = F23[k2*23 + n2];       // uniform addr -> s_load
                ar += f.x*a[n2].x - f.y*a[n2].y;
                ai += f.x*a[n2].y + f.y*a[n2].x;
            }
            X[l*368 + k1 + 16*k2] = make_float2(ar, ai);
        }
    }
    __syncthreads();

    const float sc = 0.052129458158616354f;       // 1/sqrt(368)
    for (int i = t; i < WLINES*368; i += 256){
        float2 v = X[i];
        float s = (i & 1) ? -sc : sc;             // (-1)^k
        Bo[base + i] = make_float2(v.x*s, v.y*s);
    }
}

// ---------------------------------------------------------------------------
// K3: H-axis centered IFFT, H = 640 = 16*40.
//   n = 40*n1 + n2, k = k1 + 16*k2
//   stage 1: DFT16 over n1 per (col,n2), twiddle e^{2pi i k1 n2/640}  (320 items)
//   stage 2: DFT40 over n2 per (col,k1), split in wave-uniform halves (256 units)
// ---------------------------------------------------------------------------
__global__ __launch_bounds__(320) void fftH_kernel(const float2* __restrict__ Bi,
                                                   const float2* __restrict__ F16,
                                                   const float2* __restrict__ F40,
                                                   const float2* __restrict__ TW,
                                                   float2* __restrict__ Ao){
    __shared__ float2 X[640*HPITCH];
    int t = threadIdx.x;
    int b  = blockIdx.x / (W_/HCOLS);
    int w0 = (blockIdx.x % (W_/HCOLS)) * HCOLS;
    const float2* src = Bi + (size_t)b*HW_ + w0;

    for (int i = t; i < 640*HCOLS; i += 320){
        int n = i >> 3, c = i & 7;
        float2 v = src[(size_t)n*W_ + c];
        float s = (n & 1) ? -1.f : 1.f;           // (-1)^n
        X[n*HPITCH + c] = make_float2(v.x*s, v.y*s);
    }
    __syncthreads();

    // stage 1: 8 cols * 40 n2 = 320 items, one per thread
    {
        int c = t / 40, n2 = t % 40;
        float2 xin[16];
        #pragma unroll
        for (int n1 = 0; n1 < 16; ++n1) xin[n1] = X[(40*n1 + n2)*HPITCH + c];
        for (int k1 = 0; k1 < 16; ++k1){
            float ar = 0.f, ai = 0.f;
            #pragma unroll
            for (int n1 = 0; n1 < 16; ++n1){
                float2 f = F16[k1*16 + n1];       // uniform addr -> s_load
                ar += f.x*xin[n1].x - f.y*xin[n1].y;
                ai += f.x*xin[n1].y + f.y*xin[n1].x;
            }
            float2 w = TW[k1*40 + n2];
            X[(40*k1 + n2)*HPITCH + c] = make_float2(ar*w.x - ai*w.y, ar*w.y + ai*w.x);
        }
    }
    __syncthreads();

    // stage 2: 8 cols * 16 k1 = 128 items, 2 wave-uniform halves -> 256 units
    {
        int active = (t < 256);
        int half = t >> 7;                        // waves 0-1: half 0, waves 2-3: half 1
        int idx  = t & 127;
        int c = idx >> 4, k1 = idx & 15;
        float2 a[40];
        if (active){
            #pragma unroll
            for (int n2 = 0; n2 < 40; ++n2) a[n2] = X[(40*k1 + n2)*HPITCH + c];
        }
        __syncthreads();
        if (active){
            for (int k2i = 0; k2i < 20; ++k2i){
                int k2 = half*20 + k2i;           // uniform per wave
                float ar = 0.f, ai = 0.f;
                #pragma unroll
                for (int n2 = 0; n2 < 40; ++n2){
                    float2 f = F40[k2*40 + n2];   // uniform addr -> s_load
                    ar += f.x*a[n2].x - f.y*a[n2].y;
                    ai += f.x*a[n2].y + f.y*a[n2].x;
                }
                X[(k1 + 16*k2)*HPITCH + c] = make_float2(ar, ai);
            }
        }
    }
    __syncthreads();

    const float sc = 0.03952847075210474f;        // 1/sqrt(640)
    float2* dst = Ao + (size_t)b*HW_ + w0;
    for (int i = t; i < 640*HCOLS; i += 320){
        int k = i >> 3, c = i & 7;
        float2 v = X[k*HPITCH + c];
        float s = (k & 1) ? -sc : sc;             // (-1)^k
        dst[(size_t)k*W_ + c] = make_float2(v.x*s, v.y*s);
    }
}

// ---------------------------------------------------------------------------
// K4: B-axis DFT (N=8) + magnitude + fp16-emulated conv2(1x1) + leaky
// ---------------------------------------------------------------------------
__global__ void bdft_mag_conv2_kernel(const float2* __restrict__ A,
                                      const float2* __restrict__ MB,
                                      const float* __restrict__ img,
                                      const float* __restrict__ w2,
                                      const float* __restrict__ b2,
                                      float* __restrict__ P){
    __shared__ float2 mb[64];
    int tid = threadIdx.x;
    if (tid < 64) mb[tid] = MB[tid];
    __syncthreads();

    int hw = blockIdx.x*blockDim.x + tid;
    if (hw >= HW_) return;

    float xr[8], xi[8];
    #pragma unroll
    for (int n = 0; n < 8; ++n){
        float2 x = A[n*HW_ + hw];
        xr[n] = x.x; xi[n] = x.y;
    }
    float w2h0 = __half2float(__float2half(w2[0]));
    float w2h1 = __half2float(__float2half(w2[1]));
    float b2h  = __half2float(__float2half(b2[0]));

    #pragma unroll
    for (int k = 0; k < 8; ++k){
        float yr = 0.f, yi = 0.f;
        #pragma unroll
        for (int n = 0; n < 8; ++n){
            float2 m = mb[k*8 + n];
            yr += m.x*xr[n] - m.y*xi[n];
            yi += m.x*xi[n] + m.y*xr[n];
        }
        float mag = sqrtf(yr*yr + yi*yi);
        float a = __half2float(__float2half(mag));
        float g = __half2float(__float2half(img[k*HW_ + hw]));
        float o = a*w2h0 + g*w2h1 + b2h;
        o = leaky_(o);
        o = __half2float(__float2half(o));
        P[k*HW_ + hw] = o;
    }
}

// ---------------------------------------------------------------------------
// K5: image-domain conv3x3(1->1, pad1) + leaky -> d_out
// ---------------------------------------------------------------------------
__global__ void conv_i_kernel(const float* __restrict__ P,
                              const float* __restrict__ wi,
                              const float* __restrict__ bi,
                              float* __restrict__ out){
    int idx = blockIdx.x*blockDim.x + threadIdx.x;
    if (idx >= NP_) return;
    int w = idx % W_;
    int h = (idx / W_) % H_;
    int b = idx / HW_;

    float acc = bi[0];
    #pragma unroll
    for (int dy = 0; dy < 3; ++dy){
        int hh = h + dy - 1;
        if (hh < 0 || hh >= H_) continue;
        #pragma unroll
        for (int dx = 0; dx < 3; ++dx){
            int ww = w + dx - 1;
            if (ww < 0 || ww >= W_) continue;
            acc += wi[dy*3+dx] * P[(b*H_ + hh)*W_ + ww];
        }
    }
    out[idx] = leaky_(acc);
}

// ---------------------------------------------------------------------------
// Workspace layout (bytes):
//   A      : float2[NP]    @ 0            (15,073,280)
//   B      : float2[NP]    @ 15,073,280   (15,073,280)   (P aliases B)
//   tables : float2[3457]  @ 30,146,560   (27,656)
// ---------------------------------------------------------------------------
extern "C" void kernel_launch(void* const* d_in, const int* in_sizes, int n_in,
                              void* d_out, int out_size, void* d_ws, size_t ws_size,
                              hipStream_t stream){
    const float* img = (const float*)d_in[0];
    const float* ksp = (const float*)d_in[1];
    const float* wk  = (const float*)d_in[2];
    const float* bk  = (const float*)d_in[3];
    const float* w1  = (const float*)d_in[4];
    const float* b1  = (const float*)d_in[5];
    const float* w2  = (const float*)d_in[6];
    const float* b2  = (const float*)d_in[7];
    const float* wi  = (const float*)d_in[8];
    const float* bi  = (const float*)d_in[9];

    char* ws = (char*)d_ws;
    float2* A   = (float2*)(ws + 0);
    float2* Bb  = (float2*)(ws + 15073280);
    float2* T   = (float2*)(ws + 30146560);
    float2* F16   = T + 0;
    float2* F23   = T + 256;
    float2* TW368 = T + 785;
    float2* F40   = T + 1153;
    float2* TW640 = T + 2753;
    float2* MB    = T + 3393;
    float*  P   = (float*)Bb;                 // reuse B region after H-pass
    float* out  = (float*)d_out;

    init_tables_kernel<<<14, 256, 0, stream>>>(T);

    kbranch_kernel<<<(NP_ + 255)/256, 256, 0, stream>>>(ksp, wk, bk, w1, b1, A);

    fftW_kernel<<<(B_*H_)/WLINES, 256, 0, stream>>>(A, F16, F23, TW368, Bb);   // A -> B
    fftH_kernel<<<B_*(W_/HCOLS), 320, 0, stream>>>(Bb, F16, F40, TW640, A);    // B -> A

    bdft_mag_conv2_kernel<<<(HW_ + 255)/256, 256, 0, stream>>>(A, MB, img, w2, b2, P);

    conv_i_kernel<<<(NP_ + 255)/256, 256, 0, stream>>>(P, wi, bi, out);
}

// Round 3
// 217.126 us; speedup vs baseline: 3.1420x; 1.2017x over previous
//
#include <hip/hip_runtime.h>
#include <hip/hip_fp16.h>
#include <math.h>

// Problem dims
#define B_ 8
#define H_ 640
#define W_ 368
#define HW_ (H_*W_)
#define NP_ (B_*H_*W_)   // 1,884,160

#define WLINES 8         // lines per block in W-axis FFT
#define HCOLS 4          // columns per block in H-axis FFT

__device__ __forceinline__ float leaky_(float x){ return x >= 0.f ? x : 0.01f*x; }

// ---------------------------------------------------------------------------
// Table region (float2 indices within T):
//   F16   @    0  (256)   e^{+2pi i kn/16}
//   F23   @  256  (529)   e^{+2pi i kn/23}
//   TW368 @  785  (368)   e^{+2pi i k1*n2/368}, k1 in [0,16), n2 in [0,23)
//   F8    @ 1153  (64)    e^{+2pi i kn/8}
//   F5    @ 1217  (25)    e^{+2pi i kn/5}
//   TW640 @ 1242  (640)   e^{+2pi i k1*n2/640}, k1 in [0,16), n2 in [0,40)
//   TW40  @ 1882  (40)    e^{+2pi i j1*m2/40},  j1 in [0,8),  m2 in [0,5)
//   MB    @ 1922  (64)    centered+scaled 8x8 ifft matrix
// total 1986 float2
// ---------------------------------------------------------------------------
__global__ void init_tables_kernel(float2* __restrict__ T){
    int i = blockIdx.x*blockDim.x + threadIdx.x;
    if (i >= 1986) return;
    int r, c, modN; float scale = 1.f; int cent = 0; int j;
    if      (i <  256){ j = i;        r = j/16; c = j%16; modN = 16;  }
    else if (i <  785){ j = i-256;    r = j/23; c = j%23; modN = 23;  }
    else if (i < 1153){ j = i-785;    r = j/23; c = j%23; modN = 368; }
    else if (i < 1217){ j = i-1153;   r = j/8;  c = j%8;  modN = 8;   }
    else if (i < 1242){ j = i-1217;   r = j/5;  c = j%5;  modN = 5;   }
    else if (i < 1882){ j = i-1242;   r = j/40; c = j%40; modN = 640; }
    else if (i < 1922){ j = i-1882;   r = j/5;  c = j%5;  modN = 40;  }
    else              { j = i-1922;   r = j/8;  c = j%8;  modN = 8;
                        scale = 0.35355339059327373f; cent = 1; }
    int t = (int)(((long long)r * c) % modN);
    if (t > modN/2) t -= modN;
    float ang = (float)(6.283185307179586 * ((double)t / (double)modN));
    float s, co;
    sincosf(ang, &s, &co);
    if (cent && ((r + c) & 1)) scale = -scale;
    T[i] = make_float2(co*scale, s*scale);
}

// ---------------------------------------------------------------------------
// K1: fused k-branch: conv3x3(2->32,pad1)+leaky -> conv1x1(32->2)+leaky
// ---------------------------------------------------------------------------
__global__ void kbranch_kernel(const float* __restrict__ ksp,
                               const float* __restrict__ wk,
                               const float* __restrict__ bk,
                               const float* __restrict__ w1,
                               const float* __restrict__ b1,
                               float2* __restrict__ A){
    int idx = blockIdx.x*blockDim.x + threadIdx.x;
    if (idx >= NP_) return;
    int w = idx % W_;
    int h = (idx / W_) % H_;
    int b = idx / HW_;

    float v[2][3][3];
    #pragma unroll
    for (int ic = 0; ic < 2; ++ic)
        #pragma unroll
        for (int dy = 0; dy < 3; ++dy){
            int hh = h + dy - 1;
            #pragma unroll
            for (int dx = 0; dx < 3; ++dx){
                int ww = w + dx - 1;
                v[ic][dy][dx] = (hh >= 0 && hh < H_ && ww >= 0 && ww < W_)
                              ? ksp[((b*2+ic)*H_ + hh)*W_ + ww] : 0.f;
            }
        }

    float t0 = b1[0], t1 = b1[1];
    for (int oc = 0; oc < 32; ++oc){
        float acc = bk[oc];
        #pragma unroll
        for (int ic = 0; ic < 2; ++ic)
            #pragma unroll
            for (int dy = 0; dy < 3; ++dy)
                #pragma unroll
                for (int dx = 0; dx < 3; ++dx)
                    acc += wk[((oc*2+ic)*3+dy)*3+dx] * v[ic][dy][dx];
        acc = leaky_(acc);
        t0 += w1[oc]      * acc;
        t1 += w1[32 + oc] * acc;
    }
    A[idx] = make_float2(leaky_(t0), leaky_(t1));
}

// ---------------------------------------------------------------------------
// K2: W-axis centered IFFT, W = 368 = 16*23.  8 lines/block, 640 blocks.
//   Tables in LDS (broadcast reads). X pitch 369 to break bank conflicts.
// ---------------------------------------------------------------------------
__global__ __launch_bounds__(256) void fftW_kernel(const float2* __restrict__ A,
                                                   const float2* __restrict__ Tg,
                                                   float2* __restrict__ Bo){
    __shared__ float2 X[WLINES*369];      // 23,616 B
    __shared__ float2 F16s[256];
    __shared__ float2 F23s[529];
    __shared__ float2 TWs[368];
    int t = threadIdx.x;
    for (int i = t; i < 256; i += 256) F16s[i] = Tg[i];
    for (int i = t; i < 529; i += 256) F23s[i] = Tg[256 + i];
    for (int i = t; i < 368; i += 256) TWs[i]  = Tg[785 + i];

    size_t base = (size_t)blockIdx.x * (WLINES*368);
    for (int i = t; i < WLINES*368; i += 256){
        int l = i / 368, n = i - l*368;
        float2 v = A[base + i];
        float s = (i & 1) ? -1.f : 1.f;           // (-1)^n (368 even)
        X[l*369 + n] = make_float2(v.x*s, v.y*s);
    }
    __syncthreads();

    // stage 1: DFT16 over n1 (+ twiddle): items (l,n2) = 184
    if (t < 184){
        int l = t & 7, n2 = t >> 3;
        float2 xin[16];
        #pragma unroll
        for (int n1 = 0; n1 < 16; ++n1) xin[n1] = X[l*369 + 23*n1 + n2];
        for (int k1 = 0; k1 < 16; ++k1){
            float ar = 0.f, ai = 0.f;
            #pragma unroll
            for (int n1 = 0; n1 < 16; ++n1){
                float2 f = F16s[k1*16 + n1];      // LDS broadcast
                ar += f.x*xin[n1].x - f.y*xin[n1].y;
                ai += f.x*xin[n1].y + f.y*xin[n1].x;
            }
            float2 w = TWs[k1*23 + n2];
            X[l*369 + 23*k1 + n2] = make_float2(ar*w.x - ai*w.y, ar*w.y + ai*w.x);
        }
    }
    __syncthreads();

    // stage 2: DFT23 over n2: items (l,k1,half) = 256, half covers k2 range
    {
        int l = t & 7, k1 = (t >> 3) & 15, half = t >> 7;
        float2 a[23];
        #pragma unroll
        for (int n2 = 0; n2 < 23; ++n2) a[n2] = X[l*369 + 23*k1 + n2];
        __syncthreads();
        int k2beg = half ? 12 : 0;
        int k2end = half ? 23 : 12;
        for (int k2 = k2beg; k2 < k2end; ++k2){
            float ar = 0.f, ai = 0.f;
            #pragma unroll
            for (int n2 = 0; n2 < 23; ++n2){
                float2 f = F23s[k2*23 + n2];      // LDS broadcast
                ar += f.x*a[n2].x - f.y*a[n2].y;
                ai += f.x*a[n2].y + f.y*a[n2].x;
            }
            X[l*369 + k1 + 16*k2] = make_float2(ar, ai);
        }
    }
    __syncthreads();

    const float sc = 0.052129458158616354f;       // 1/sqrt(368)
    for (int i = t; i < WLINES*368; i += 256){
        int l = i / 368, k = i - l*368;
        float2 v = X[l*369 + k];
        float s = (i & 1) ? -sc : sc;             // (-1)^k
        Bo[base + i] = make_float2(v.x*s, v.y*s);
    }
}

// ---------------------------------------------------------------------------
// K3: H-axis centered IFFT, H = 640 = 16*8*5.  4 cols/block, 736 blocks.
//   stage 1 : DFT16 over n1 (+ TW640 twiddle)
//   stage 2a: DFT8 over m1  (+ TW40 twiddle)      (n2 = 5*m1 + m2)
//   stage 2b: DFT5 over m2                        (k2 = j1 + 8*j2)
//   final k = k1 + 16*j1 + 128*j2.  X pitch 5 float2.
// ---------------------------------------------------------------------------
__global__ __launch_bounds__(256) void fftH_kernel(const float2* __restrict__ Bi,
                                                   const float2* __restrict__ Tg,
                                                   float2* __restrict__ Ao){
    __shared__ float2 X[640*5];           // 25,600 B
    __shared__ float2 F16s[256];
    __shared__ float2 F8s[64];
    __shared__ float2 F5s[25];
    __shared__ float2 TW640s[640];
    __shared__ float2 TW40s[40];
    int t = threadIdx.x;
    for (int i = t; i < 256; i += 256) F16s[i] = Tg[i];
    if (t < 64) F8s[t] = Tg[1153 + t];
    if (t < 25) F5s[t] = Tg[1217 + t];
    for (int i = t; i < 640; i += 256) TW640s[i] = Tg[1242 + i];
    if (t < 40) TW40s[t] = Tg[1882 + t];

    int b  = blockIdx.x / 92;
    int w0 = (blockIdx.x - b*92) * HCOLS;
    const float2* src = Bi + (size_t)b*HW_ + w0;

    for (int i = t; i < 640*HCOLS; i += 256){
        int n = i >> 2, c = i & 3;
        float2 v = src[(size_t)n*W_ + c];
        float s = (n & 1) ? -1.f : 1.f;           // (-1)^n
        X[n*5 + c] = make_float2(v.x*s, v.y*s);
    }
    __syncthreads();

    // stage 1: items (c,n2) = 160
    if (t < 160){
        int c = t & 3, n2 = t >> 2;
        float2 xin[16];
        #pragma unroll
        for (int n1 = 0; n1 < 16; ++n1) xin[n1] = X[(40*n1 + n2)*5 + c];
        for (int k1 = 0; k1 < 16; ++k1){
            float ar = 0.f, ai = 0.f;
            #pragma unroll
            for (int n1 = 0; n1 < 16; ++n1){
                float2 f = F16s[k1*16 + n1];      // LDS broadcast
                ar += f.x*xin[n1].x - f.y*xin[n1].y;
                ai += f.x*xin[n1].y + f.y*xin[n1].x;
            }
            float2 w = TW640s[k1*40 + n2];
            X[(40*k1 + n2)*5 + c] = make_float2(ar*w.x - ai*w.y, ar*w.y + ai*w.x);
        }
    }
    __syncthreads();

    // stage 2a: DFT8 over m1, items (c,k1,m2) = 320 (each item in-place safe)
    for (int it = t; it < 320; it += 256){
        int c = it & 3, k1 = (it >> 2) & 15, m2 = it >> 6;
        float2 g[8];
        #pragma unroll
        for (int m1 = 0; m1 < 8; ++m1) g[m1] = X[(40*k1 + 5*m1 + m2)*5 + c];
        #pragma unroll
        for (int j1 = 0; j1 < 8; ++j1){
            float ar = 0.f, ai = 0.f;
            #pragma unroll
            for (int m1 = 0; m1 < 8; ++m1){
                float2 f = F8s[j1*8 + m1];        // LDS broadcast
                ar += f.x*g[m1].x - f.y*g[m1].y;
                ai += f.x*g[m1].y + f.y*g[m1].x;
            }
            float2 w = TW40s[j1*5 + m2];
            X[(40*k1 + 5*j1 + m2)*5 + c] = make_float2(ar*w.x - ai*w.y, ar*w.y + ai*w.x);
        }
    }
    __syncthreads();

    // stage 2b: DFT5 over m2, items (c,k1,j1) = 512 -> 2 per thread,
    // load both into regs, barrier, then write (cross-item slot exchange).
    {
        int it0 = t,        c0 = it0 & 3, k10 = (it0 >> 2) & 15, j10 = it0 >> 6;
        int it1 = t + 256;  int c1 = it1 & 3, k11 = (it1 >> 2) & 15, j11 = it1 >> 6;
        float2 p0[5], p1[5];
        #pragma unroll
        for (int m2 = 0; m2 < 5; ++m2) p0[m2] = X[(40*k10 + 5*j10 + m2)*5 + c0];
        #pragma unroll
        for (int m2 = 0; m2 < 5; ++m2) p1[m2] = X[(40*k11 + 5*j11 + m2)*5 + c1];
        __syncthreads();
        #pragma unroll
        for (int j2 = 0; j2 < 5; ++j2){
            float ar = 0.f, ai = 0.f, br = 0.f, bi2 = 0.f;
            #pragma unroll
            for (int m2 = 0; m2 < 5; ++m2){
                float2 f = F5s[j2*5 + m2];        // LDS broadcast
                ar  += f.x*p0[m2].x - f.y*p0[m2].y;
                ai  += f.x*p0[m2].y + f.y*p0[m2].x;
                br  += f.x*p1[m2].x - f.y*p1[m2].y;
                bi2 += f.x*p1[m2].y + f.y*p1[m2].x;
            }
            X[(k10 + 16*j10 + 128*j2)*5 + c0] = make_float2(ar, ai);
            X[(k11 + 16*j11 + 128*j2)*5 + c1] = make_float2(br, bi2);
        }
    }
    __syncthreads();

    const float sc = 0.03952847075210474f;        // 1/sqrt(640)
    float2* dst = Ao + (size_t)b*HW_ + w0;
    for (int i = t; i < 640*HCOLS; i += 256){
        int k = i >> 2, c = i & 3;
        float2 v = X[k*5 + c];
        float s = (k & 1) ? -sc : sc;             // (-1)^k
        dst[(size_t)k*W_ + c] = make_float2(v.x*s, v.y*s);
    }
}

// ---------------------------------------------------------------------------
// K4: B-axis DFT (N=8) + magnitude + fp16-emulated conv2(1x1) + leaky
// ---------------------------------------------------------------------------
__global__ void bdft_mag_conv2_kernel(const float2* __restrict__ A,
                                      const float2* __restrict__ MB,
                                      const float* __restrict__ img,
                                      const float* __restrict__ w2,
                                      const float* __restrict__ b2,
                                      float* __restrict__ P){
    __shared__ float2 mb[64];
    int tid = threadIdx.x;
    if (tid < 64) mb[tid] = MB[tid];
    __syncthreads();

    int hw = blockIdx.x*blockDim.x + tid;
    if (hw >= HW_) return;

    float xr[8], xi[8];
    #pragma unroll
    for (int n = 0; n < 8; ++n){
        float2 x = A[n*HW_ + hw];
        xr[n] = x.x; xi[n] = x.y;
    }
    float w2h0 = __half2float(__float2half(w2[0]));
    float w2h1 = __half2float(__float2half(w2[1]));
    float b2h  = __half2float(__float2half(b2[0]));

    #pragma unroll
    for (int k = 0; k < 8; ++k){
        float yr = 0.f, yi = 0.f;
        #pragma unroll
        for (int n = 0; n < 8; ++n){
            float2 m = mb[k*8 + n];
            yr += m.x*xr[n] - m.y*xi[n];
            yi += m.x*xi[n] + m.y*xr[n];
        }
        float mag = sqrtf(yr*yr + yi*yi);
        float a = __half2float(__float2half(mag));
        float g = __half2float(__float2half(img[k*HW_ + hw]));
        float o = a*w2h0 + g*w2h1 + b2h;
        o = leaky_(o);
        o = __half2float(__float2half(o));
        P[k*HW_ + hw] = o;
    }
}

// ---------------------------------------------------------------------------
// K5: image-domain conv3x3(1->1, pad1) + leaky -> d_out
// ---------------------------------------------------------------------------
__global__ void conv_i_kernel(const float* __restrict__ P,
                              const float* __restrict__ wi,
                              const float* __restrict__ bi,
                              float* __restrict__ out){
    int idx = blockIdx.x*blockDim.x + threadIdx.x;
    if (idx >= NP_) return;
    int w = idx % W_;
    int h = (idx / W_) % H_;
    int b = idx / HW_;

    float acc = bi[0];
    #pragma unroll
    for (int dy = 0; dy < 3; ++dy){
        int hh = h + dy - 1;
        if (hh < 0 || hh >= H_) continue;
        #pragma unroll
        for (int dx = 0; dx < 3; ++dx){
            int ww = w + dx - 1;
            if (ww < 0 || ww >= W_) continue;
            acc += wi[dy*3+dx] * P[(b*H_ + hh)*W_ + ww];
        }
    }
    out[idx] = leaky_(acc);
}

// ---------------------------------------------------------------------------
// Workspace layout (bytes):
//   A      : float2[NP]    @ 0            (15,073,280)
//   B      : float2[NP]    @ 15,073,280   (15,073,280)   (P aliases B)
//   tables : float2[1986]  @ 30,146,560   (15,888)
// ---------------------------------------------------------------------------
extern "C" void kernel_launch(void* const* d_in, const int* in_sizes, int n_in,
                              void* d_out, int out_size, void* d_ws, size_t ws_size,
                              hipStream_t stream){
    const float* img = (const float*)d_in[0];
    const float* ksp = (const float*)d_in[1];
    const float* wk  = (const float*)d_in[2];
    const float* bk  = (const float*)d_in[3];
    const float* w1  = (const float*)d_in[4];
    const float* b1  = (const float*)d_in[5];
    const float* w2  = (const float*)d_in[6];
    const float* b2  = (const float*)d_in[7];
    const float* wi  = (const float*)d_in[8];
    const float* bi  = (const float*)d_in[9];

    char* ws = (char*)d_ws;
    float2* A   = (float2*)(ws + 0);
    float2* Bb  = (float2*)(ws + 15073280);
    float2* T   = (float2*)(ws + 30146560);
    float2* MB  = T + 1922;
    float*  P   = (float*)Bb;                 // reuse B region after H-pass
    float* out  = (float*)d_out;

    init_tables_kernel<<<8, 256, 0, stream>>>(T);

    kbranch_kernel<<<(NP_ + 255)/256, 256, 0, stream>>>(ksp, wk, bk, w1, b1, A);

    fftW_kernel<<<(B_*H_)/WLINES, 256, 0, stream>>>(A, T, Bb);     // A -> B
    fftH_kernel<<<B_*(W_/HCOLS), 256, 0, stream>>>(Bb, T, A);      // B -> A

    bdft_mag_conv2_kernel<<<(HW_ + 255)/256, 256, 0, stream>>>(A, MB, img, w2, b2, P);

    conv_i_kernel<<<(NP_ + 255)/256, 256, 0, stream>>>(P, wi, bi, out);
}

// Round 5
// 190.091 us; speedup vs baseline: 3.5888x; 1.1422x over previous
//
#include <hip/hip_runtime.h>
#include <hip/hip_fp16.h>
#include <math.h>

// Problem dims
#define B_ 8
#define H_ 640
#define W_ 368
#define HW_ (H_*W_)
#define NP_ (B_*H_*W_)   // 1,884,160

#define WLINES 8         // lines per block in W-axis FFT
#define HCOLS 4          // columns per block in H-axis FFT

__device__ __forceinline__ float leaky_(float x){ return x >= 0.f ? x : 0.01f*x; }

__device__ __forceinline__ float2 cadd_(float2 a, float2 b){ return make_float2(a.x+b.x, a.y+b.y); }
__device__ __forceinline__ float2 csub_(float2 a, float2 b){ return make_float2(a.x-b.x, a.y-b.y); }
// multiply by e^{+i theta} given (c,s)
__device__ __forceinline__ float2 cmul_(float2 a, float c, float s){
    return make_float2(a.x*c - a.y*s, a.x*s + a.y*c);
}
__device__ __forceinline__ float2 cmulv_(float2 a, float2 w){
    return make_float2(a.x*w.x - a.y*w.y, a.x*w.y + a.y*w.x);
}

// DFT4 with +i convention: Z[j] = sum_m y[m] * i^{jm}
__device__ __forceinline__ void dft4p_(float2 p0, float2 p1, float2 p2, float2 p3,
                                       float2& z0, float2& z1, float2& z2, float2& z3){
    float2 s0 = cadd_(p0,p2), d0 = csub_(p0,p2);
    float2 s1 = cadd_(p1,p3), d1 = csub_(p1,p3);
    z0 = cadd_(s0,s1);
    z2 = csub_(s0,s1);
    z1 = make_float2(d0.x - d1.y, d0.y + d1.x);   // d0 + i*d1
    z3 = make_float2(d0.x + d1.y, d0.y - d1.x);   // d0 - i*d1
}

// 16-point DFT, +i convention: X[k] = sum_n x[n] e^{+2pi i kn/16}
__device__ __forceinline__ void fft16p_(const float2* x, float2* X){
    const float C1 = 0.9238795325112867f, S1 = 0.3826834323650898f;
    const float R  = 0.7071067811865476f;
    float2 Y[4][4];
    #pragma unroll
    for (int b = 0; b < 4; ++b)
        dft4p_(x[b], x[4+b], x[8+b], x[12+b], Y[b][0], Y[b][1], Y[b][2], Y[b][3]);
    // twiddle Y[b][c] *= w16^{b*c}
    Y[1][1] = cmul_(Y[1][1],  C1,  S1);
    Y[1][2] = cmul_(Y[1][2],   R,   R);
    Y[1][3] = cmul_(Y[1][3],  S1,  C1);
    Y[2][1] = cmul_(Y[2][1],   R,   R);
    Y[2][2] = make_float2(-Y[2][2].y, Y[2][2].x);          // *i
    Y[2][3] = cmul_(Y[2][3],  -R,   R);
    Y[3][1] = cmul_(Y[3][1],  S1,  C1);
    Y[3][2] = cmul_(Y[3][2],  -R,   R);
    Y[3][3] = cmul_(Y[3][3], -C1, -S1);
    #pragma unroll
    for (int c = 0; c < 4; ++c)
        dft4p_(Y[0][c], Y[1][c], Y[2][c], Y[3][c], X[c], X[c+4], X[c+8], X[c+12]);
}

// 8-point DFT, +i convention
__device__ __forceinline__ void fft8p_(const float2* x, float2* X){
    const float R = 0.7071067811865476f;
    float2 Y0[4], Y1[4];
    dft4p_(x[0], x[2], x[4], x[6], Y0[0], Y0[1], Y0[2], Y0[3]);
    dft4p_(x[1], x[3], x[5], x[7], Y1[0], Y1[1], Y1[2], Y1[3]);
    float2 T0 = Y1[0];
    float2 T1 = cmul_(Y1[1],  R, R);
    float2 T2 = make_float2(-Y1[2].y, Y1[2].x);            // *i
    float2 T3 = cmul_(Y1[3], -R, R);
    X[0] = cadd_(Y0[0], T0);  X[4] = csub_(Y0[0], T0);
    X[1] = cadd_(Y0[1], T1);  X[5] = csub_(Y0[1], T1);
    X[2] = cadd_(Y0[2], T2);  X[6] = csub_(Y0[2], T2);
    X[3] = cadd_(Y0[3], T3);  X[7] = csub_(Y0[3], T3);
}

// ---------------------------------------------------------------------------
// Tables (float2 indices in T):
//   TW368P @    0 (368)  [n2*16+k1] = e^{+2pi i k1 n2/368}, n2<23,k1<16
//   TW640P @  368 (640)  [n2*16+k1] = e^{+2pi i k1 n2/640}, n2<40,k1<16
//   TW40P  @ 1008 ( 40)  [m2*8+j1]  = e^{+2pi i j1 m2/40},  m2<5, j1<8
//   F23P   @ 1048 (253)  [k2*11+m-1]= (cos,sin)(2pi k2 m/23), m=1..11
//   MB     @ 1301 ( 64)  centered+scaled 8x8 ifft matrix
// total 1365
// ---------------------------------------------------------------------------
__global__ void init_tables_kernel(float2* __restrict__ T){
    int i = blockIdx.x*blockDim.x + threadIdx.x;
    if (i >= 1365) return;
    int r, c, modN; float scale = 1.f; int cent = 0; int j;
    if      (i <  368){ j = i;        r = j%16; c = j/16; modN = 368; }
    else if (i < 1008){ j = i-368;    r = j%16; c = j/16; modN = 640; }
    else if (i < 1048){ j = i-1008;   r = j%8;  c = j/8;  modN = 40;  }
    else if (i < 1301){ j = i-1048;   r = j/11; c = j%11 + 1; modN = 23; }
    else              { j = i-1301;   r = j/8;  c = j%8;  modN = 8;
                        scale = 0.35355339059327373f; cent = 1; }
    int t = (int)(((long long)r * c) % modN);
    if (t > modN/2) t -= modN;
    float ang = (float)(6.283185307179586 * ((double)t / (double)modN));
    float s, co;
    sincosf(ang, &s, &co);
    if (cent && ((r + c) & 1)) scale = -scale;
    T[i] = make_float2(co*scale, s*scale);
}

// ---------------------------------------------------------------------------
// K1: fused k-branch, 4-pixel strips. conv3x3(2->32)+leaky -> conv1x1(32->2)+leaky
// in[ic][r][j] holds column w0-1+j (j=0..5); halo j=5 is column w0+4 = p[4].
// ---------------------------------------------------------------------------
__global__ __launch_bounds__(256) void kbranch_kernel(const float* __restrict__ ksp,
                               const float* __restrict__ wk,
                               const float* __restrict__ bk,
                               const float* __restrict__ w1,
                               const float* __restrict__ b1,
                               float2* __restrict__ A){
    int tid = blockIdx.x*256 + threadIdx.x;          // NP_/4 threads exactly
    int ws  = tid % 92;
    int rem = tid / 92;
    int h   = rem % 640;
    int b   = rem / 640;
    int w0  = ws*4;

    float in[2][3][6];
    bool cm0 = (ws > 0), cm5 = (ws < 91);
    int  e0off = cm0 ? -1 : 0;                       // dummy in-bounds when masked
    int  e5off = cm5 ?  4 : 3;                       // column w0+4 (FIX: was 5)
    #pragma unroll
    for (int r = 0; r < 3; ++r){
        int hh = h - 1 + r;
        bool rm = (hh >= 0) && (hh < 640);
        int hc = min(max(hh, 0), 639);
        #pragma unroll
        for (int ic = 0; ic < 2; ++ic){
            const float* p = ksp + (((b*2+ic)*640) + hc)*368 + w0;
            float  e0 = p[e0off];
            float4 q  = *(const float4*)p;           // w0 aligned 16B
            float  e5 = p[e5off];
            in[ic][r][0] = (rm && cm0) ? e0 : 0.f;
            in[ic][r][1] = rm ? q.x : 0.f;
            in[ic][r][2] = rm ? q.y : 0.f;
            in[ic][r][3] = rm ? q.z : 0.f;
            in[ic][r][4] = rm ? q.w : 0.f;
            in[ic][r][5] = (rm && cm5) ? e5 : 0.f;
        }
    }

    float o0[4], o1[4];
    #pragma unroll
    for (int p = 0; p < 4; ++p){ o0[p] = b1[0]; o1[p] = b1[1]; }

    #pragma unroll 2
    for (int oc = 0; oc < 32; ++oc){
        float a[4];
        float bo = bk[oc];
        #pragma unroll
        for (int p = 0; p < 4; ++p) a[p] = bo;
        #pragma unroll
        for (int ic = 0; ic < 2; ++ic)
            #pragma unroll
            for (int dy = 0; dy < 3; ++dy)
                #pragma unroll
                for (int dx = 0; dx < 3; ++dx){
                    float wv = wk[((oc*2+ic)*3+dy)*3+dx];
                    #pragma unroll
                    for (int p = 0; p < 4; ++p)
                        a[p] += wv * in[ic][dy][p+dx];
                }
        float wa = w1[oc], wb = w1[32+oc];
        #pragma unroll
        for (int p = 0; p < 4; ++p){
            float l = leaky_(a[p]);
            o0[p] += wa * l;
            o1[p] += wb * l;
        }
    }

    size_t idx = (size_t)(b*640 + h)*368 + w0;
    float4 s0 = make_float4(leaky_(o0[0]), leaky_(o1[0]), leaky_(o0[1]), leaky_(o1[1]));
    float4 s1 = make_float4(leaky_(o0[2]), leaky_(o1[2]), leaky_(o0[3]), leaky_(o1[3]));
    ((float4*)(A + idx))[0] = s0;
    ((float4*)(A + idx))[1] = s1;
}

// ---------------------------------------------------------------------------
// K2: W-axis centered IFFT, W = 368 = 16*23.  8 lines/block, 640 blocks.
//   stage1: FFT16 (radix-4 butterflies) + TW368 twiddle (global, L1)
//   stage2: DFT23 via conjugate pairs; F23P rows via wave-uniform s_loads
// ---------------------------------------------------------------------------
__global__ __launch_bounds__(256) void fftW_kernel(const float2* __restrict__ A,
                                                   const float2* __restrict__ TW368P,
                                                   const float2* __restrict__ F23P,
                                                   float2* __restrict__ Bo){
    __shared__ float2 X[WLINES*369];      // 23,616 B
    int t = threadIdx.x;
    size_t base = (size_t)blockIdx.x * (WLINES*368);

    for (int i = t; i < WLINES*368; i += 256){
        int l = i / 368, n = i - l*368;
        float2 v = A[base + i];
        float s = (i & 1) ? -1.f : 1.f;            // (-1)^n
        X[l*369 + n] = make_float2(v.x*s, v.y*s);
    }
    __syncthreads();

    // stage 1: items (l,n2) = 184
    if (t < 184){
        int l = t & 7, n2 = t >> 3;
        float2 xr[16], Xo[16];
        #pragma unroll
        for (int n1 = 0; n1 < 16; ++n1) xr[n1] = X[l*369 + 23*n1 + n2];
        fft16p_(xr, Xo);
        const float2* row = TW368P + n2*16;
        #pragma unroll
        for (int k1 = 0; k1 < 16; ++k1)
            X[l*369 + 23*k1 + n2] = cmulv_(Xo[k1], row[k1]);
    }
    __syncthreads();

    // stage 2: DFT23 via pairs; 256 units = (l,k1,half)
    {
        int l = t & 7, k1 = (t >> 3) & 15, half = t >> 7;
        const float2* xp = X + l*369 + 23*k1;
        float2 x0 = xp[0];
        float2 u[11], d[11];
        #pragma unroll
        for (int m = 1; m <= 11; ++m){
            float2 a = xp[m], bb = xp[23-m];
            u[m-1] = cadd_(a, bb);
            d[m-1] = csub_(a, bb);
        }
        __syncthreads();
        int k2beg = half ? 12 : 0;
        int k2end = half ? 23 : 12;
        for (int k2 = k2beg; k2 < k2end; ++k2){
            const float2* row = F23P + k2*11;      // wave-uniform -> s_load
            float re = x0.x, im = x0.y;
            #pragma unroll
            for (int m = 0; m < 11; ++m){
                float c = row[m].x, s = row[m].y;
                re += u[m].x*c - d[m].y*s;
                im += u[m].y*c + d[m].x*s;
            }
            X[l*369 + k1 + 16*k2] = make_float2(re, im);
        }
    }
    __syncthreads();

    const float sc = 0.052129458158616354f;        // 1/sqrt(368)
    for (int i = t; i < WLINES*368; i += 256){
        int l = i / 368, k = i - l*368;
        float2 v = X[l*369 + k];
        float s = (i & 1) ? -sc : sc;              // (-1)^k
        Bo[base + i] = make_float2(v.x*s, v.y*s);
    }
}

// ---------------------------------------------------------------------------
// K3: H-axis centered IFFT, H = 640 = 16*8*5.  4 cols/block, 736 blocks.
//   stage1 : FFT16 butterflies + TW640 (global, L1)
//   stage2a: FFT8 butterflies + TW40 (global, L1)
//   stage2b: DFT5 via pairs, hard-coded constants
// ---------------------------------------------------------------------------
__global__ __launch_bounds__(256) void fftH_kernel(const float2* __restrict__ Bi,
                                                   const float2* __restrict__ TW640P,
                                                   const float2* __restrict__ TW40P,
                                                   float2* __restrict__ Ao){
    __shared__ float2 X[640*5];           // 25,600 B
    int t = threadIdx.x;
    int b  = blockIdx.x / 92;
    int w0 = (blockIdx.x - b*92) * HCOLS;
    const float2* src = Bi + (size_t)b*HW_ + w0;

    for (int i = t; i < 640*HCOLS; i += 256){
        int n = i >> 2, c = i & 3;
        float2 v = src[(size_t)n*W_ + c];
        float s = (n & 1) ? -1.f : 1.f;            // (-1)^n
        X[n*5 + c] = make_float2(v.x*s, v.y*s);
    }
    __syncthreads();

    // stage 1: items (c,n2) = 160
    if (t < 160){
        int c = t & 3, n2 = t >> 2;
        float2 xr[16], Xo[16];
        #pragma unroll
        for (int n1 = 0; n1 < 16; ++n1) xr[n1] = X[(40*n1 + n2)*5 + c];
        fft16p_(xr, Xo);
        const float2* row = TW640P + n2*16;
        #pragma unroll
        for (int k1 = 0; k1 < 16; ++k1)
            X[(40*k1 + n2)*5 + c] = cmulv_(Xo[k1], row[k1]);
    }
    __syncthreads();

    // stage 2a: FFT8 over m1, items (c,k1,m2) = 320 (in-place safe per item)
    for (int it = t; it < 320; it += 256){
        int c = it & 3, k1 = (it >> 2) & 15, m2 = it >> 6;
        float2 xr[8], Xo[8];
        #pragma unroll
        for (int m1 = 0; m1 < 8; ++m1) xr[m1] = X[(40*k1 + 5*m1 + m2)*5 + c];
        fft8p_(xr, Xo);
        const float2* row = TW40P + m2*8;
        #pragma unroll
        for (int j1 = 0; j1 < 8; ++j1)
            X[(40*k1 + 5*j1 + m2)*5 + c] = cmulv_(Xo[j1], row[j1]);
    }
    __syncthreads();

    // stage 2b: DFT5 over m2 via pairs, items (c,k1,j1) = 512 -> 2/thread
    {
        const float CK1[5] = {1.f,  0.30901699437494745f, -0.8090169943749475f, -0.8090169943749475f,  0.30901699437494745f};
        const float SK1[5] = {0.f,  0.9510565162951535f,   0.5877852522924731f, -0.5877852522924731f, -0.9510565162951535f};
        const float CK2[5] = {1.f, -0.8090169943749475f,   0.30901699437494745f, 0.30901699437494745f, -0.8090169943749475f};
        const float SK2[5] = {0.f,  0.5877852522924731f,  -0.9510565162951535f,  0.9510565162951535f, -0.5877852522924731f};
        int it0 = t, it1 = t + 256;
        int c0 = it0 & 3, k10 = (it0 >> 2) & 15, j10 = it0 >> 6;
        int c1 = it1 & 3, k11 = (it1 >> 2) & 15, j11 = it1 >> 6;
        float2 p0[5], p1[5];
        #pragma unroll
        for (int m2 = 0; m2 < 5; ++m2) p0[m2] = X[(40*k10 + 5*j10 + m2)*5 + c0];
        #pragma unroll
        for (int m2 = 0; m2 < 5; ++m2) p1[m2] = X[(40*k11 + 5*j11 + m2)*5 + c1];
        __syncthreads();
        float2 u0a = cadd_(p0[1], p0[4]), d0a = csub_(p0[1], p0[4]);
        float2 u0b = cadd_(p0[2], p0[3]), d0b = csub_(p0[2], p0[3]);
        float2 u1a = cadd_(p1[1], p1[4]), d1a = csub_(p1[1], p1[4]);
        float2 u1b = cadd_(p1[2], p1[3]), d1b = csub_(p1[2], p1[3]);
        #pragma unroll
        for (int j2 = 0; j2 < 5; ++j2){
            float c1v = CK1[j2], s1v = SK1[j2], c2v = CK2[j2], s2v = SK2[j2];
            float re0 = p0[0].x + u0a.x*c1v - d0a.y*s1v + u0b.x*c2v - d0b.y*s2v;
            float im0 = p0[0].y + u0a.y*c1v + d0a.x*s1v + u0b.y*c2v + d0b.x*s2v;
            float re1 = p1[0].x + u1a.x*c1v - d1a.y*s1v + u1b.x*c2v - d1b.y*s2v;
            float im1 = p1[0].y + u1a.y*c1v + d1a.x*s1v + u1b.y*c2v + d1b.x*s2v;
            X[(k10 + 16*j10 + 128*j2)*5 + c0] = make_float2(re0, im0);
            X[(k11 + 16*j11 + 128*j2)*5 + c1] = make_float2(re1, im1);
        }
    }
    __syncthreads();

    const float sc = 0.03952847075210474f;         // 1/sqrt(640)
    float2* dst = Ao + (size_t)b*HW_ + w0;
    for (int i = t; i < 640*HCOLS; i += 256){
        int k = i >> 2, c = i & 3;
        float2 v = X[k*5 + c];
        float s = (k & 1) ? -sc : sc;              // (-1)^k
        dst[(size_t)k*W_ + c] = make_float2(v.x*s, v.y*s);
    }
}

// ---------------------------------------------------------------------------
// K4: B-axis DFT (N=8) + magnitude + fp16-emulated conv2(1x1) + leaky
// ---------------------------------------------------------------------------
__global__ void bdft_mag_conv2_kernel(const float2* __restrict__ A,
                                      const float2* __restrict__ MB,
                                      const float* __restrict__ img,
                                      const float* __restrict__ w2,
                                      const float* __restrict__ b2,
                                      float* __restrict__ P){
    __shared__ float2 mb[64];
    int tid = threadIdx.x;
    if (tid < 64) mb[tid] = MB[tid];
    __syncthreads();

    int hw = blockIdx.x*blockDim.x + tid;
    if (hw >= HW_) return;

    float xr[8], xi[8];
    #pragma unroll
    for (int n = 0; n < 8; ++n){
        float2 x = A[n*HW_ + hw];
        xr[n] = x.x; xi[n] = x.y;
    }
    float w2h0 = __half2float(__float2half(w2[0]));
    float w2h1 = __half2float(__float2half(w2[1]));
    float b2h  = __half2float(__float2half(b2[0]));

    #pragma unroll
    for (int k = 0; k < 8; ++k){
        float yr = 0.f, yi = 0.f;
        #pragma unroll
        for (int n = 0; n < 8; ++n){
            float2 m = mb[k*8 + n];
            yr += m.x*xr[n] - m.y*xi[n];
            yi += m.x*xi[n] + m.y*xr[n];
        }
        float mag = sqrtf(yr*yr + yi*yi);
        float a = __half2float(__float2half(mag));
        float g = __half2float(__float2half(img[k*HW_ + hw]));
        float o = a*w2h0 + g*w2h1 + b2h;
        o = leaky_(o);
        o = __half2float(__float2half(o));
        P[k*HW_ + hw] = o;
    }
}

// ---------------------------------------------------------------------------
// K5: image-domain conv3x3(1->1, pad1) + leaky -> d_out
// ---------------------------------------------------------------------------
__global__ void conv_i_kernel(const float* __restrict__ P,
                              const float* __restrict__ wi,
                              const float* __restrict__ bi,
                              float* __restrict__ out){
    int idx = blockIdx.x*blockDim.x + threadIdx.x;
    if (idx >= NP_) return;
    int w = idx % W_;
    int h = (idx / W_) % H_;
    int b = idx / HW_;

    float acc = bi[0];
    #pragma unroll
    for (int dy = 0; dy < 3; ++dy){
        int hh = h + dy - 1;
        if (hh < 0 || hh >= H_) continue;
        #pragma unroll
        for (int dx = 0; dx < 3; ++dx){
            int ww = w + dx - 1;
            if (ww < 0 || ww >= W_) continue;
            acc += wi[dy*3+dx] * P[(b*H_ + hh)*W_ + ww];
        }
    }
    out[idx] = leaky_(acc);
}

// ---------------------------------------------------------------------------
// Workspace layout (bytes):
//   A      : float2[NP]    @ 0            (15,073,280)
//   B      : float2[NP]    @ 15,073,280   (15,073,280)   (P aliases B)
//   tables : float2[1365]  @ 30,146,560   (10,920)
// ---------------------------------------------------------------------------
extern "C" void kernel_launch(void* const* d_in, const int* in_sizes, int n_in,
                              void* d_out, int out_size, void* d_ws, size_t ws_size,
                              hipStream_t stream){
    const float* img = (const float*)d_in[0];
    const float* ksp = (const float*)d_in[1];
    const float* wk  = (const float*)d_in[2];
    const float* bk  = (const float*)d_in[3];
    const float* w1  = (const float*)d_in[4];
    const float* b1  = (const float*)d_in[5];
    const float* w2  = (const float*)d_in[6];
    const float* b2  = (const float*)d_in[7];
    const float* wi  = (const float*)d_in[8];
    const float* bi  = (const float*)d_in[9];

    char* ws = (char*)d_ws;
    float2* A   = (float2*)(ws + 0);
    float2* Bb  = (float2*)(ws + 15073280);
    float2* T   = (float2*)(ws + 30146560);
    float2* TW368P = T + 0;
    float2* TW640P = T + 368;
    float2* TW40P  = T + 1008;
    float2* F23P   = T + 1048;
    float2* MB     = T + 1301;
    float*  P   = (float*)Bb;                 // reuse B region after H-pass
    float* out  = (float*)d_out;

    init_tables_kernel<<<6, 256, 0, stream>>>(T);

    kbranch_kernel<<<NP_/4/256, 256, 0, stream>>>(ksp, wk, bk, w1, b1, A);

    fftW_kernel<<<(B_*H_)/WLINES, 256, 0, stream>>>(A, TW368P, F23P, Bb);   // A -> B
    fftH_kernel<<<B_*(W_/HCOLS), 256, 0, stream>>>(Bb, TW640P, TW40P, A);   // B -> A

    bdft_mag_conv2_kernel<<<(HW_ + 255)/256, 256, 0, stream>>>(A, MB, img, w2, b2, P);

    conv_i_kernel<<<(NP_ + 255)/256, 256, 0, stream>>>(P, wi, bi, out);
}